// Round 4
// baseline (411.343 us; speedup 1.0000x reference)
//
#include <hip/hip_runtime.h>
#include <stdint.h>

// Problem constants (B=4, N=4096, D_MODEL=1024, H=16, Dh=64, K_EIG=16)
#define NTOK   16384          // B*N tokens
#define DM     1024           // d_model (GEMM K)
#define NQKV   3072           // folded output features: [Qf|Kf|Vf], each 16*64

typedef __attribute__((ext_vector_type(8))) _Float16 half8;
typedef __attribute__((ext_vector_type(4))) _Float16 half4;
typedef __attribute__((ext_vector_type(4))) float    float4v;

__device__ __forceinline__ void async_cp16(const void* g, void* l){
  __builtin_amdgcn_global_load_lds(
      (const __attribute__((address_space(1))) void*)g,
      (__attribute__((address_space(3))) void*)l, 16, 0, 0);
}

// ---------------- x fp32 -> fp16 ----------------
__global__ void cvt_x_kernel(const float* __restrict__ x, _Float16* __restrict__ xb){
  int i = (blockIdx.x * blockDim.x + threadIdx.x) * 4;
  const int stride = gridDim.x * blockDim.x * 4;
  for(; i < NTOK * DM; i += stride){
    float4v v = *(const float4v*)(x + i);
    half4 o;
    o[0]=(_Float16)v[0]; o[1]=(_Float16)v[1]; o[2]=(_Float16)v[2]; o[3]=(_Float16)v[3];
    *(half4*)(xb + i) = o;
  }
}

// ---------------- fold E,w into weights; output pre-transposed WT[n][c] fp16 ----------------
// n = p*1024 + kE*64 + d ;  WT[n][c] = fw[kE] * sum_h E[h][kE] * Wp[c][h*64+d]
__global__ __launch_bounds__(256)
void prep_w_kernel(const float* __restrict__ Wq, const float* __restrict__ Wk,
                   const float* __restrict__ Wv, const float* __restrict__ E,
                   const float* __restrict__ fw, _Float16* __restrict__ WT){
  __shared__ float Wl[64][65];     // [c_local][d], pad 65 -> bank = (c+d)%32, 2-way free
  __shared__ float sEv[256];
  const int t  = threadIdx.x;
  const int bx = blockIdx.x;                 // 0..191
  const int p  = bx >> 6, kg = (bx >> 4) & 3, ct = bx & 15;
  const float* W = (p == 0) ? Wq : (p == 1) ? Wk : Wv;
  sEv[t] = E[t];                             // E is 16x16 = 256 floats
  const int c_l = t & 63, dg = t >> 6;       // lane = c_l (conflict-free LDS reads)
  const int c0 = ct * 64;
  float acc[4][16];
  #pragma unroll
  for(int ke = 0; ke < 4; ++ke)
    #pragma unroll
    for(int i = 0; i < 16; ++i) acc[ke][i] = 0.f;

  for(int h = 0; h < 16; ++h){
    __syncthreads();                         // previous iteration's readers done
    #pragma unroll
    for(int j = 0; j < 16; ++j){             // stage 64x64 fp32 chunk, coalesced
      const int flat = j * 256 + t;
      const int rowc = flat >> 6, cold = flat & 63;
      Wl[rowc][cold] = W[(size_t)(c0 + rowc) * 1024 + h * 64 + cold];
    }
    __syncthreads();
    float ew[4];
    #pragma unroll
    for(int ke = 0; ke < 4; ++ke) ew[ke] = sEv[h * 16 + kg * 4 + ke];
    #pragma unroll
    for(int i = 0; i < 16; ++i){
      const float w = Wl[c_l][dg * 16 + i];
      #pragma unroll
      for(int ke = 0; ke < 4; ++ke) acc[ke][i] += ew[ke] * w;
    }
  }
  #pragma unroll
  for(int ke = 0; ke < 4; ++ke){
    const int kE = kg * 4 + ke;
    const float s = fw[kE];
    #pragma unroll
    for(int i = 0; i < 16; ++i){
      const int n = (p * 16 + kE) * 64 + dg * 16 + i;
      WT[(size_t)n * 1024 + c0 + c_l] = (_Float16)(acc[ke][i] * s);  // lanes c_l: coalesced
    }
  }
}

// ---------------- folded bias fb[n] (fp32) ----------------
__global__ void prep_b_kernel(const float* __restrict__ bq, const float* __restrict__ bk,
                              const float* __restrict__ bv, const float* __restrict__ E,
                              const float* __restrict__ fw, float* __restrict__ fb){
  const int n = blockIdx.x * blockDim.x + threadIdx.x;
  if(n >= NQKV) return;
  const int p = n >> 10, kE = (n >> 6) & 15, d = n & 63;
  const float* b = (p == 0) ? bq : (p == 1) ? bk : bv;
  float acc = 0.f;
  for(int h = 0; h < 16; ++h) acc += E[h * 16 + kE] * b[h * 64 + d];
  fb[n] = acc * fw[kE];
}

// ---------------- m97-style GEMM: QKVf[m][n] = xb[m][:] . WT[n][:]  (+bias), fp16 out ----------------
__global__ __launch_bounds__(256)
void gemm_qkv_kernel(const _Float16* __restrict__ A,   // [NTOK][1024] fp16
                     const _Float16* __restrict__ BT,  // [3072][1024] fp16 (pre-transposed)
                     const float* __restrict__ bias,   // [3072] fp32
                     _Float16* __restrict__ C){        // [NTOK][3072] fp16
  __shared__ _Float16 As[128 * 32];
  __shared__ _Float16 Bs[128 * 32];
  const int t = threadIdx.x;
  const int lane = t & 63, wv = t >> 6;
  const int l15 = lane & 15, q = lane >> 4;
  const int m0 = blockIdx.y * 128, n0 = blockIdx.x * 128;
  const int wm = (wv & 1) * 64, wn = (wv >> 1) * 64;

  float4v acc[4][4];
  #pragma unroll
  for(int i = 0; i < 4; ++i)
    #pragma unroll
    for(int j = 0; j < 4; ++j){ acc[i][j][0]=0.f; acc[i][j][1]=0.f; acc[i][j][2]=0.f; acc[i][j][3]=0.f; }

  const int ar = t >> 2;            // staging row 0..63
  const int ac = (t & 3) * 8;       // staging k-offset (8 fp16 = 16B)
  const _Float16* ga0 = A  + (size_t)(m0 + ar)      * 1024 + ac;
  const _Float16* ga1 = A  + (size_t)(m0 + 64 + ar) * 1024 + ac;
  const _Float16* gb0 = BT + (size_t)(n0 + ar)      * 1024 + ac;
  const _Float16* gb1 = BT + (size_t)(n0 + 64 + ar) * 1024 + ac;

  for(int k0 = 0; k0 < 1024; k0 += 32){
    async_cp16(ga0 + k0, As + t * 8);
    async_cp16(ga1 + k0, As + 2048 + t * 8);
    async_cp16(gb0 + k0, Bs + t * 8);
    async_cp16(gb1 + k0, Bs + 2048 + t * 8);
    __syncthreads();
    half8 af[4], bf[4];
    #pragma unroll
    for(int i = 0; i < 4; ++i) af[i] = *(const half8*)(As + (wm + i * 16 + l15) * 32 + q * 8);
    #pragma unroll
    for(int j = 0; j < 4; ++j) bf[j] = *(const half8*)(Bs + (wn + j * 16 + l15) * 32 + q * 8);
    #pragma unroll
    for(int i = 0; i < 4; ++i)
      #pragma unroll
      for(int j = 0; j < 4; ++j)
        acc[i][j] = __builtin_amdgcn_mfma_f32_16x16x32_f16(af[i], bf[j], acc[i][j], 0, 0, 0);
    __syncthreads();
  }
  #pragma unroll
  for(int j = 0; j < 4; ++j){
    const int n = n0 + wn + j * 16 + l15;
    const float bs = bias[n];
    #pragma unroll
    for(int i = 0; i < 4; ++i){
      const int mg = m0 + wm + i * 16 + q * 4;
      #pragma unroll
      for(int r = 0; r < 4; ++r)
        C[(size_t)(mg + r) * NQKV + n] = (_Float16)(acc[i][j][r] + bs);
    }
  }
}

// ---------------- per-token spectral attention, LDS-staged, S^T orientation ----------------
// S^T = Kf Qf^T (lane holds S[k=l15][l=q*4+r]) -> softmax over (regs,q) = 4 shfl
// P -> pT[l][k] -> B-frag contiguous; G = E@P -> gT[h][l] -> A-frag contiguous; out = G@Vf.
// Zero-padded k>=16 halves: BOTH A-side (sE, gT) and B-side (pT) upper columns are zeroed —
// MFMA is IEEE-propagating, 0 x uninit-LDS can be 0 x NaN = NaN (round-3 bug).
__global__ __launch_bounds__(256)
void attn_kernel(const _Float16* __restrict__ QKV,   // [NTOK][3072] fp16
                 const float* __restrict__ E,        // [16][16] fp32
                 float* __restrict__ out){           // [NTOK][1024] fp32
  __shared__ _Float16 sQ[4 * 3072];                  // 24KB: 4 tokens, token-major
  __shared__ _Float16 sE[16 * 32];                   // [h][k], cols 16..31 zero
  __shared__ _Float16 pT[4][16 * 32];                // per-wave [l][k], cols 16..31 zero
  __shared__ _Float16 gT[4][16 * 32];                // per-wave [h][l], cols 16..31 zero

  const int t = threadIdx.x, lane = t & 63, wv = t >> 6;
  const int l15 = lane & 15, q = lane >> 4;

  // init sE (fold E to fp16, zero-pad upper k) and zero pT/gT upper halves
  {
    #pragma unroll
    for(int s = 0; s < 2; ++s){
      const int idx = s * 256 + t;                   // 0..511
      const int row = idx >> 5, col = idx & 31;
      sE[idx] = (col < 16) ? (_Float16)E[row * 16 + col] : (_Float16)0.f;
    }
    #pragma unroll
    for(int s = 0; s < 4; ++s){
      const int idx = s * 256 + t;                   // 0..1023 -> [4][16][16..31]
      const int w = idx >> 8, rem = idx & 255;
      const int off = (rem >> 4) * 32 + 16 + (rem & 15);
      pT[w][off] = (_Float16)0.f;
      gT[w][off] = (_Float16)0.f;
    }
  }

  // stage 4 tokens (24KB) via async global->LDS, fully sequential
  const _Float16* gb = QKV + (size_t)blockIdx.x * (4 * 3072);
  #pragma unroll
  for(int i = 0; i < 6; ++i) async_cp16(gb + (i * 256 + t) * 8, sQ + (i * 256 + t) * 8);
  __syncthreads();

  const int tok = blockIdx.x * 4 + wv;
  const _Float16* tb = sQ + wv * 3072;

  // ---- S^T = Kf Qf^T : A = Kf rows, B = Qf rows (identical contiguous b128 patterns)
  half8 aK0 = *(const half8*)(tb + 1024 + l15 * 64 + q * 8);
  half8 aK1 = *(const half8*)(tb + 1024 + l15 * 64 + 32 + q * 8);
  half8 bQ0 = *(const half8*)(tb + l15 * 64 + q * 8);
  half8 bQ1 = *(const half8*)(tb + l15 * 64 + 32 + q * 8);
  float4v S; S[0]=0.f; S[1]=0.f; S[2]=0.f; S[3]=0.f;
  S = __builtin_amdgcn_mfma_f32_16x16x32_f16(aK0, bQ0, S, 0, 0, 0);
  S = __builtin_amdgcn_mfma_f32_16x16x32_f16(aK1, bQ1, S, 0, 0, 0);
  // lane holds S[k=l15][l=q*4+r] * 8 ; softmax over l = (regs, q-groups)

  float v[4];
  #pragma unroll
  for(int r = 0; r < 4; ++r) v[r] = S[r] * 0.125f;
  float mx = fmaxf(fmaxf(v[0], v[1]), fmaxf(v[2], v[3]));
  mx = fmaxf(mx, __shfl_xor(mx, 16));
  mx = fmaxf(mx, __shfl_xor(mx, 32));
  float e[4];
  #pragma unroll
  for(int r = 0; r < 4; ++r) e[r] = __expf(v[r] - mx);
  float sm = (e[0] + e[1]) + (e[2] + e[3]);
  sm += __shfl_xor(sm, 16);
  sm += __shfl_xor(sm, 32);
  const float rs = 1.f / sm;

  // ---- P -> pT[l][k]
  _Float16* pw = pT[wv];
  #pragma unroll
  for(int r = 0; r < 4; ++r) pw[(q * 4 + r) * 32 + l15] = (_Float16)(e[r] * rs);
  half8 bP = *(const half8*)(pw + l15 * 32 + q * 8);          // B[k][n=l], zeros k>=16
  half8 aE = *(const half8*)(sE + l15 * 32 + q * 8);          // A[m=h][k], zeros k>=16

  float4v G; G[0]=0.f; G[1]=0.f; G[2]=0.f; G[3]=0.f;
  G = __builtin_amdgcn_mfma_f32_16x16x32_f16(aE, bP, G, 0, 0, 0);
  // lane holds G[h=q*4+r][l=l15]

  // ---- G -> gT[h][l]
  _Float16* gw = gT[wv];
  #pragma unroll
  for(int r = 0; r < 4; ++r) gw[(q * 4 + r) * 32 + l15] = (_Float16)G[r];
  half8 aG = *(const half8*)(gw + l15 * 32 + q * 8);          // A[m=h][k=l], zeros k>=16

  // ---- out = G @ Vf : B-frag gathered from LDS (k>=16 lanes re-read k-16, killed by aG zeros;
  //      sQ data is finite so 0 x finite = 0 is safe here)
  const _Float16* vb = tb + 2048 + (q & 1) * 8 * 64;
  float* ob = out + (size_t)tok * 1024;
  #pragma unroll
  for(int tt = 0; tt < 4; ++tt){
    half8 vf;
    #pragma unroll
    for(int jj = 0; jj < 8; ++jj) vf[jj] = vb[jj * 64 + tt * 16 + l15];
    float4v O; O[0]=0.f; O[1]=0.f; O[2]=0.f; O[3]=0.f;
    O = __builtin_amdgcn_mfma_f32_16x16x32_f16(aG, vf, O, 0, 0, 0);
    #pragma unroll
    for(int r = 0; r < 4; ++r)
      ob[(q * 4 + r) * 64 + tt * 16 + l15] = O[r];
  }
}

extern "C" void kernel_launch(void* const* d_in, const int* in_sizes, int n_in,
                              void* d_out, int out_size, void* d_ws, size_t ws_size,
                              hipStream_t stream){
  const float* x  = (const float*)d_in[0];
  const float* Wq = (const float*)d_in[1];
  const float* bq = (const float*)d_in[2];
  const float* Wk = (const float*)d_in[3];
  const float* bk = (const float*)d_in[4];
  const float* Wv = (const float*)d_in[5];
  const float* bv = (const float*)d_in[6];
  const float* E  = (const float*)d_in[7];
  const float* fw = (const float*)d_in[8];
  float* out = (float*)d_out;

  // workspace layout (needs 136 MB)
  char* ws = (char*)d_ws;
  _Float16* xb  = (_Float16*)ws;                                  // 32 MB
  _Float16* WT  = (_Float16*)(ws + (size_t)32 * 1024 * 1024);     //  6 MB
  float*    fb  = (float*)   (ws + (size_t)39 * 1024 * 1024);     // 12 KB
  _Float16* QKV = (_Float16*)(ws + (size_t)40 * 1024 * 1024);     // 96 MB

  hipLaunchKernelGGL(cvt_x_kernel, dim3(4096), dim3(256), 0, stream, x, xb);
  hipLaunchKernelGGL(prep_w_kernel, dim3(192), dim3(256), 0, stream, Wq, Wk, Wv, E, fw, WT);
  hipLaunchKernelGGL(prep_b_kernel, dim3(12), dim3(256), 0, stream, bq, bk, bv, E, fw, fb);
  hipLaunchKernelGGL(gemm_qkv_kernel, dim3(24, 128), dim3(256), 0, stream, xb, WT, fb, QKV);
  hipLaunchKernelGGL(attn_kernel, dim3(NTOK / 4), dim3(256), 0, stream, QKV, E, out);
}

// Round 5
// 309.286 us; speedup vs baseline: 1.3300x; 1.3300x over previous
//
#include <hip/hip_runtime.h>
#include <stdint.h>

// Problem constants (B=4, N=4096, D_MODEL=1024, H=16, Dh=64, K_EIG=16)
#define NTOK   16384          // B*N tokens
#define DM     1024           // d_model (GEMM K)
#define NQKV   3072           // folded output features: [Qf|Kf|Vf], each 16*64

typedef __attribute__((ext_vector_type(8))) _Float16 half8;
typedef __attribute__((ext_vector_type(4))) _Float16 half4;
typedef __attribute__((ext_vector_type(4))) float    float4v;

__device__ __forceinline__ void async_cp16(const void* g, void* l){
  __builtin_amdgcn_global_load_lds(
      (const __attribute__((address_space(1))) void*)g,
      (__attribute__((address_space(3))) void*)l, 16, 0, 0);
}

// ---------------- x fp32 -> fp16 (16-B stores) ----------------
__global__ void cvt_x_kernel(const float* __restrict__ x, _Float16* __restrict__ xb){
  int i = (blockIdx.x * blockDim.x + threadIdx.x) * 8;
  const int stride = gridDim.x * blockDim.x * 8;
  for(; i < NTOK * DM; i += stride){
    float4v v0 = *(const float4v*)(x + i);
    float4v v1 = *(const float4v*)(x + i + 4);
    half8 o;
    o[0]=(_Float16)v0[0]; o[1]=(_Float16)v0[1]; o[2]=(_Float16)v0[2]; o[3]=(_Float16)v0[3];
    o[4]=(_Float16)v1[0]; o[5]=(_Float16)v1[1]; o[6]=(_Float16)v1[2]; o[7]=(_Float16)v1[3];
    *(half8*)(xb + i) = o;
  }
}

// ---------------- fold E,w into weights; WT[n][c] fp16, W read ONCE ----------------
// n = p*1024 + kE*64 + d ;  WT[n][c] = fw[kE] * sum_h E[h][kE] * Wp[c][h*64+d]
// block = (p, 8-row c-tile): contiguous 32KB read, register fold, LDS transpose, 16B stores.
__global__ __launch_bounds__(256)
void prep_w_kernel(const float* __restrict__ Wq, const float* __restrict__ Wk,
                   const float* __restrict__ Wv, const float* __restrict__ E,
                   const float* __restrict__ fw, _Float16* __restrict__ WT){
  __shared__ float Wl[8][1032];            // padded rows
  __shared__ float oT[16][8][65];          // [kE][c][d], pad 65 -> conflict-free
  __shared__ float sEv[256];
  __shared__ float sFw[16];
  const int t  = threadIdx.x;
  const int bx = blockIdx.x;               // 0..383
  const int p  = bx >> 7, rt = bx & 127;   // p in 0..2, rt in 0..127
  const int c0 = rt * 8;
  const float* W = (p == 0) ? Wq : (p == 1) ? Wk : Wv;
  sEv[t] = E[t];
  if(t < 16) sFw[t] = fw[t];

  // load 8 full rows (8192 floats), fully coalesced & contiguous
  #pragma unroll
  for(int j = 0; j < 32; ++j){
    const int flat = j * 256 + t;          // 0..8191
    const int row = flat >> 10, col = flat & 1023;
    Wl[row][col] = W[(size_t)(c0 + row) * 1024 + col];
  }
  __syncthreads();

  // fold: thread (d = t&63, rg = t>>6) handles rows rg*2, rg*2+1
  const int d = t & 63, rg = t >> 6;
  #pragma unroll
  for(int rr = 0; rr < 2; ++rr){
    const int row = rg * 2 + rr;
    float w[16];
    #pragma unroll
    for(int h = 0; h < 16; ++h) w[h] = Wl[row][h * 64 + d];
    #pragma unroll
    for(int ke = 0; ke < 16; ++ke){
      float acc = 0.f;
      #pragma unroll
      for(int h = 0; h < 16; ++h) acc += sEv[h * 16 + ke] * w[h];
      oT[ke][row][d] = acc * sFw[ke];
    }
  }
  __syncthreads();

  // write: thread handles 4 (kE,d) pairs, each a 16-B (8 x fp16) chunk of c
  #pragma unroll
  for(int k4 = 0; k4 < 4; ++k4){
    const int idx = k4 * 256 + t;          // 0..1023
    const int ke = idx >> 6, dd = idx & 63;
    half8 o;
    #pragma unroll
    for(int c = 0; c < 8; ++c) o[c] = (_Float16)oT[ke][c][dd];
    const int n = (p * 16 + ke) * 64 + dd;
    *(half8*)(WT + (size_t)n * 1024 + c0) = o;
  }
}

// ---------------- folded bias fb[n] (fp32) ----------------
__global__ void prep_b_kernel(const float* __restrict__ bq, const float* __restrict__ bk,
                              const float* __restrict__ bv, const float* __restrict__ E,
                              const float* __restrict__ fw, float* __restrict__ fb){
  const int n = blockIdx.x * blockDim.x + threadIdx.x;
  if(n >= NQKV) return;
  const int p = n >> 10, kE = (n >> 6) & 15, d = n & 63;
  const float* b = (p == 0) ? bq : (p == 1) ? bk : bv;
  float acc = 0.f;
  for(int h = 0; h < 16; ++h) acc += E[h * 16 + kE] * b[h * 64 + d];
  fb[n] = acc * fw[kE];
}

// ---------------- m97-style GEMM + XCD-aware swizzle ----------------
__global__ __launch_bounds__(256)
void gemm_qkv_kernel(const _Float16* __restrict__ A,   // [NTOK][1024] fp16
                     const _Float16* __restrict__ BT,  // [3072][1024] fp16
                     const float* __restrict__ bias,   // [3072] fp32
                     _Float16* __restrict__ C){        // [NTOK][3072] fp16
  __shared__ _Float16 As[128 * 32];
  __shared__ _Float16 Bs[128 * 32];
  const int t = threadIdx.x;
  const int lane = t & 63, wv = t >> 6;
  const int l15 = lane & 15, q = lane >> 4;
  // XCD swizzle: band of 16 m-tiles per XCD, n iterated slowly -> A band + B tile L2-hot
  const int l = blockIdx.x + blockIdx.y * 24;   // 0..3071
  const int xcd = l & 7, s = l >> 3;            // s in 0..383
  const int m0 = (xcd * 16 + (s & 15)) * 128;
  const int n0 = (s >> 4) * 128;
  const int wm = (wv & 1) * 64, wn = (wv >> 1) * 64;

  float4v acc[4][4];
  #pragma unroll
  for(int i = 0; i < 4; ++i)
    #pragma unroll
    for(int j = 0; j < 4; ++j){ acc[i][j][0]=0.f; acc[i][j][1]=0.f; acc[i][j][2]=0.f; acc[i][j][3]=0.f; }

  const int ar = t >> 2;            // staging row 0..63
  const int ac = (t & 3) * 8;       // staging k-offset (8 fp16 = 16B)
  const _Float16* ga0 = A  + (size_t)(m0 + ar)      * 1024 + ac;
  const _Float16* ga1 = A  + (size_t)(m0 + 64 + ar) * 1024 + ac;
  const _Float16* gb0 = BT + (size_t)(n0 + ar)      * 1024 + ac;
  const _Float16* gb1 = BT + (size_t)(n0 + 64 + ar) * 1024 + ac;

  for(int k0 = 0; k0 < 1024; k0 += 32){
    async_cp16(ga0 + k0, As + t * 8);
    async_cp16(ga1 + k0, As + 2048 + t * 8);
    async_cp16(gb0 + k0, Bs + t * 8);
    async_cp16(gb1 + k0, Bs + 2048 + t * 8);
    __syncthreads();
    half8 af[4], bf[4];
    #pragma unroll
    for(int i = 0; i < 4; ++i) af[i] = *(const half8*)(As + (wm + i * 16 + l15) * 32 + q * 8);
    #pragma unroll
    for(int j = 0; j < 4; ++j) bf[j] = *(const half8*)(Bs + (wn + j * 16 + l15) * 32 + q * 8);
    #pragma unroll
    for(int i = 0; i < 4; ++i)
      #pragma unroll
      for(int j = 0; j < 4; ++j)
        acc[i][j] = __builtin_amdgcn_mfma_f32_16x16x32_f16(af[i], bf[j], acc[i][j], 0, 0, 0);
    __syncthreads();
  }
  #pragma unroll
  for(int j = 0; j < 4; ++j){
    const int n = n0 + wn + j * 16 + l15;
    const float bs = bias[n];
    #pragma unroll
    for(int i = 0; i < 4; ++i){
      const int mg = m0 + wm + i * 16 + q * 4;
      #pragma unroll
      for(int r = 0; r < 4; ++r)
        C[(size_t)(mg + r) * NQKV + n] = (_Float16)(acc[i][j][r] + bs);
    }
  }
}

// ---------------- per-token spectral attention v3 ----------------
// Qf/Kf frags: direct coalesced b128 global loads (round-2 pattern, conflict-free).
// Only V staged to LDS (8 KB). S^T = Kf Qf^T -> softmax over (regs,q) = 4 shfl.
// pT/gT upper k-halves zeroed (MFMA is IEEE-propagating: 0 x uninit = NaN).
__global__ __launch_bounds__(256)
void attn_kernel(const _Float16* __restrict__ QKV,   // [NTOK][3072] fp16
                 const float* __restrict__ E,        // [16][16] fp32
                 float* __restrict__ out){           // [NTOK][1024] fp32
  __shared__ _Float16 sV[4 * 1024];                  // 8KB: V slice of 4 tokens
  __shared__ _Float16 sE[16 * 32];                   // [h][k], cols 16..31 zero
  __shared__ _Float16 pT[4][16 * 32];                // per-wave [l][k], cols 16..31 zero
  __shared__ _Float16 gT[4][16 * 32];                // per-wave [h][l], cols 16..31 zero

  const int t = threadIdx.x, lane = t & 63, wv = t >> 6;
  const int l15 = lane & 15, q = lane >> 4;

  // init sE + zero pT/gT upper halves
  {
    #pragma unroll
    for(int s = 0; s < 2; ++s){
      const int idx = s * 256 + t;                   // 0..511
      const int row = idx >> 5, col = idx & 31;
      sE[idx] = (col < 16) ? (_Float16)E[row * 16 + col] : (_Float16)0.f;
    }
    #pragma unroll
    for(int s = 0; s < 4; ++s){
      const int idx = s * 256 + t;                   // 0..1023 -> [4][16][16..31]
      const int w = idx >> 8, rem = idx & 255;
      const int off = (rem >> 4) * 32 + 16 + (rem & 15);
      pT[w][off] = (_Float16)0.f;
      gT[w][off] = (_Float16)0.f;
    }
  }

  // stage V of 4 tokens: LDS dest contiguous (wave-uniform base + lane*16)
  const _Float16* gb = QKV + (size_t)blockIdx.x * (4 * 3072);
  #pragma unroll
  for(int i = 0; i < 2; ++i){
    const int f = i * 256 + t;                       // 8-half chunk index, 0..511
    async_cp16(gb + (f >> 7) * 3072 + 2048 + (f & 127) * 8, sV + f * 8);
  }

  const int tok = blockIdx.x * 4 + wv;
  const _Float16* tg = QKV + (size_t)tok * 3072;

  // ---- S^T = Kf Qf^T, frags straight from global (coalesced 16B/lane)
  half8 aK0 = *(const half8*)(tg + 1024 + l15 * 64 + q * 8);
  half8 aK1 = *(const half8*)(tg + 1024 + l15 * 64 + 32 + q * 8);
  half8 bQ0 = *(const half8*)(tg + l15 * 64 + q * 8);
  half8 bQ1 = *(const half8*)(tg + l15 * 64 + 32 + q * 8);
  float4v S; S[0]=0.f; S[1]=0.f; S[2]=0.f; S[3]=0.f;
  S = __builtin_amdgcn_mfma_f32_16x16x32_f16(aK0, bQ0, S, 0, 0, 0);
  S = __builtin_amdgcn_mfma_f32_16x16x32_f16(aK1, bQ1, S, 0, 0, 0);
  // lane holds S[k=l15][l=q*4+r]*8 ; softmax over l = (regs, q-groups)

  float v[4];
  #pragma unroll
  for(int r = 0; r < 4; ++r) v[r] = S[r] * 0.125f;
  float mx = fmaxf(fmaxf(v[0], v[1]), fmaxf(v[2], v[3]));
  mx = fmaxf(mx, __shfl_xor(mx, 16));
  mx = fmaxf(mx, __shfl_xor(mx, 32));
  float e[4];
  #pragma unroll
  for(int r = 0; r < 4; ++r) e[r] = __expf(v[r] - mx);
  float sm = (e[0] + e[1]) + (e[2] + e[3]);
  sm += __shfl_xor(sm, 16);
  sm += __shfl_xor(sm, 32);
  const float rs = 1.f / sm;

  __syncthreads();   // sV staged + init complete

  // ---- P -> pT[l][k]
  _Float16* pw = pT[wv];
  #pragma unroll
  for(int r = 0; r < 4; ++r) pw[(q * 4 + r) * 32 + l15] = (_Float16)(e[r] * rs);
  half8 bP = *(const half8*)(pw + l15 * 32 + q * 8);          // B[k][n=l], zeros k>=16
  half8 aE = *(const half8*)(sE + l15 * 32 + q * 8);          // A[m=h][k], zeros k>=16

  float4v G; G[0]=0.f; G[1]=0.f; G[2]=0.f; G[3]=0.f;
  G = __builtin_amdgcn_mfma_f32_16x16x32_f16(aE, bP, G, 0, 0, 0);
  // lane holds G[h=q*4+r][l=l15]

  // ---- G -> gT[h][l]
  _Float16* gw = gT[wv];
  #pragma unroll
  for(int r = 0; r < 4; ++r) gw[(q * 4 + r) * 32 + l15] = (_Float16)G[r];
  half8 aG = *(const half8*)(gw + l15 * 32 + q * 8);          // A[m=h][k=l], zeros k>=16

  // ---- out = G @ Vf : B-frag from sV (k>=16 lanes re-read k-16, killed by aG zeros)
  const _Float16* vb = sV + wv * 1024 + (q & 1) * 8 * 64;
  float* ob = out + (size_t)tok * 1024;
  #pragma unroll
  for(int tt = 0; tt < 4; ++tt){
    half8 vf;
    #pragma unroll
    for(int jj = 0; jj < 8; ++jj) vf[jj] = vb[jj * 64 + tt * 16 + l15];
    float4v O; O[0]=0.f; O[1]=0.f; O[2]=0.f; O[3]=0.f;
    O = __builtin_amdgcn_mfma_f32_16x16x32_f16(aG, vf, O, 0, 0, 0);
    #pragma unroll
    for(int r = 0; r < 4; ++r)
      ob[(q * 4 + r) * 64 + tt * 16 + l15] = O[r];
  }
}

extern "C" void kernel_launch(void* const* d_in, const int* in_sizes, int n_in,
                              void* d_out, int out_size, void* d_ws, size_t ws_size,
                              hipStream_t stream){
  const float* x  = (const float*)d_in[0];
  const float* Wq = (const float*)d_in[1];
  const float* bq = (const float*)d_in[2];
  const float* Wk = (const float*)d_in[3];
  const float* bk = (const float*)d_in[4];
  const float* Wv = (const float*)d_in[5];
  const float* bv = (const float*)d_in[6];
  const float* E  = (const float*)d_in[7];
  const float* fw = (const float*)d_in[8];
  float* out = (float*)d_out;

  // workspace layout (needs 136 MB)
  char* ws = (char*)d_ws;
  _Float16* xb  = (_Float16*)ws;                                  // 32 MB
  _Float16* WT  = (_Float16*)(ws + (size_t)32 * 1024 * 1024);     //  6 MB
  float*    fb  = (float*)   (ws + (size_t)39 * 1024 * 1024);     // 12 KB
  _Float16* QKV = (_Float16*)(ws + (size_t)40 * 1024 * 1024);     // 96 MB

  hipLaunchKernelGGL(cvt_x_kernel, dim3(2048), dim3(256), 0, stream, x, xb);
  hipLaunchKernelGGL(prep_w_kernel, dim3(384), dim3(256), 0, stream, Wq, Wk, Wv, E, fw, WT);
  hipLaunchKernelGGL(prep_b_kernel, dim3(12), dim3(256), 0, stream, bq, bk, bv, E, fw, fb);
  hipLaunchKernelGGL(gemm_qkv_kernel, dim3(24, 128), dim3(256), 0, stream, xb, WT, fb, QKV);
  hipLaunchKernelGGL(attn_kernel, dim3(NTOK / 4), dim3(256), 0, stream, QKV, E, out);
}